// Round 12
// baseline (2440.265 us; speedup 1.0000x reference)
//
#include <hip/hip_runtime.h>
#include <stdint.h>

// Problem constants
#define MROWS 32768      // B*S = 8*4096
#define KD    256        // 2*DIM
#define VOCABN 8192

typedef _Float16 half8  __attribute__((ext_vector_type(8)));
typedef _Float16 half4v __attribute__((ext_vector_type(4)));
typedef float  floatx4  __attribute__((ext_vector_type(4)));

#define LDA 528    // A LDS row stride: 512 B data + 16 B pad
#define LDKB 144   // B LDS row stride: 128 B data + 16 B pad (R4/R10-proven)

// scratch layout (byte offsets within d_ws; ws_size >= WS_NEED verified R3/R4)
#define A_OFF     0u          // f16 z  [32768][256]  = 16,777,216 B
#define B_OFF     16777216u   // f16 cb [8192][256]   =  4,194,304 B
#define CN_OFF    20971520u   // f32 0.5*||c||^2 [8192] = 32,768 B
#define PART_OFF  21004288u   // float4 top2 [32768][8] = 4,194,304 B
#define IDX_OFF   25198592u   // int idx [32768] = 131,072 B
#define WS_NEED   25329664u

// ---- top-2 (max sigma) with smaller-index tie-break ----
struct Top2 { float s1; int i1; float s2; int i2; };

__device__ __forceinline__ bool better(float sa, int ia, float sb, int ib) {
    return (sa > sb) || (sa == sb && ia < ib);
}
__device__ __forceinline__ Top2 merge2(const Top2& a, const Top2& b) {
    Top2 r;
    if (better(b.s1, b.i1, a.s1, a.i1)) {
        r.s1 = b.s1; r.i1 = b.i1;
        if (better(a.s1, a.i1, b.s2, b.i2)) { r.s2 = a.s1; r.i2 = a.i1; }
        else                                { r.s2 = b.s2; r.i2 = b.i2; }
    } else {
        r.s1 = a.s1; r.i1 = a.i1;
        if (better(b.s1, b.i1, a.s2, a.i2)) { r.s2 = b.s1; r.i2 = b.i1; }
        else                                { r.s2 = a.s2; r.i2 = a.i2; }
    }
    return r;
}

// ---- 1. z = concat(real,imag) as f16 [32768][256] ----
__global__ __launch_bounds__(256) void prep_z(const float* __restrict__ gr,
                                              const float* __restrict__ gi,
                                              _Float16* __restrict__ A) {
    int t = blockIdx.x * 256 + threadIdx.x;     // 4 elements/thread
    int base = t * 4;
    int m = base >> 8;
    int k = base & 255;
    float4 v;
    if (k < 128) v = *(const float4*)(gr + (size_t)m * 128 + k);
    else         v = *(const float4*)(gi + (size_t)m * 128 + (k - 128));
    half4v h;
    h[0] = (_Float16)v.x; h[1] = (_Float16)v.y;
    h[2] = (_Float16)v.z; h[3] = (_Float16)v.w;
    *(half4v*)(A + base) = h;
}

// ---- 2. codebook f16 [8192][256] + 0.5*||c||^2 fp32 ----
__global__ __launch_bounds__(64) void prep_c(const float* __restrict__ cb,
                                             _Float16* __restrict__ B,
                                             float* __restrict__ cnorm) {
    int v = blockIdx.x;
    int lane = threadIdx.x;                    // 0..63, 4 floats each
    float4 c = ((const float4*)(cb + (size_t)v * 256))[lane];
    half4v h;
    h[0] = (_Float16)c.x; h[1] = (_Float16)c.y;
    h[2] = (_Float16)c.z; h[3] = (_Float16)c.w;
    ((half4v*)(B + (size_t)v * 256))[lane] = h;
    float s = c.x * c.x + c.y * c.y + c.z * c.z + c.w * c.w;
    #pragma unroll
    for (int m = 32; m; m >>= 1) s += __shfl_xor(s, m);
    if (lane == 0) cnorm[v] = 0.5f * s;
}

// ---- 3. f16 GEMM + per-row top-2 argmax(sigma) ----
// R11 post-mortem: 4 blocks/CU occupancy worked (42%) but register-held B
// prefetch + __launch_bounds__(256,4) caused scratch spills (WRITE_SIZE
// 13 MB -> 1.8 GB, VGPR 88 -> 52) = the whole regression. This round keeps
// BM=32 / grid 1024 / 4 blocks/CU but restores R10's proven staging order:
// loads issued at stage top (pre-barrier, briefly live), no min-waves bound.
__global__ __launch_bounds__(256) void gemm_argmin(const _Float16* __restrict__ A,
                                                   const _Float16* __restrict__ B,
                                                   const float* __restrict__ cnorm,
                                                   float4* __restrict__ part) {
    __shared__ __align__(16) char   Asm[32 * LDA];     // 16,896 B
    __shared__ __align__(16) char   Bs[128 * LDKB];    // 18,432 B
    __shared__ __align__(16) float4 topbuf[128];       // [32 rows][4 col-waves]
    __shared__ __align__(16) float4 rowtop[32];        // per-row running top2

    const int tid = threadIdx.x;
    const int m0 = blockIdx.x * 32;
    const int wave = tid >> 6, lane = tid & 63;
    const int wc = wave;                               // 1x4: 32 rows x 32 cols/wave
    const int lane16 = lane & 15, quad = lane >> 4;

    // one-time A-tile stage: 32 rows x 512 B; 8 threads/row, 64 B each
    {
        int r = tid >> 3, qo = (tid & 7) * 32;         // f16 element offset
        const _Float16* ag = A + (size_t)(m0 + r) * 256 + qo;
        char* al = Asm + r * LDA + qo * 2;
        uint4 tmp[4];
        #pragma unroll
        for (int i = 0; i < 4; ++i) tmp[i] = *(const uint4*)(ag + i * 8);
        #pragma unroll
        for (int i = 0; i < 4; ++i) *(uint4*)(al + i * 16) = tmp[i];
    }
    if (tid < 32)
        rowtop[tid] = make_float4(-3.4e38f, __int_as_float(0x7fffffff),
                                  -3.4e38f, __int_as_float(0x7fffffff));

    for (int g = 0; g < 64; ++g) {
        const int n0 = g * 128;

        float hc[2];
        #pragma unroll
        for (int j = 0; j < 2; ++j)
            hc[j] = cnorm[n0 + wc * 32 + j * 16 + lane16];

        floatx4 acc[2][2];
        #pragma unroll
        for (int i = 0; i < 2; ++i)
            #pragma unroll
            for (int j = 0; j < 2; ++j)
                acc[i][j] = (floatx4){0.f, 0.f, 0.f, 0.f};

        for (int s = 0; s < 4; ++s) {
            const int k0 = s * 64;
            // B tile: 128 rows x 64 f16 = 1024 16B chunks; 4/thread (R10 order:
            // loads issued pre-barrier, overlap prior stage's MFMA tail)
            uint4 bv[4];
            #pragma unroll
            for (int it = 0; it < 4; ++it) {
                int c = it * 256 + tid;        // 0..1023
                int r = c >> 3, ci = c & 7;
                bv[it] = *(const uint4*)(B + (size_t)(n0 + r) * 256 + k0 + ci * 8);
            }
            __syncthreads();   // prior stage's Bs reads done (covers A/rowtop at g0s0)
            #pragma unroll
            for (int it = 0; it < 4; ++it) {
                int c = it * 256 + tid;
                *(uint4*)(Bs + (c >> 3) * LDKB + (c & 7) * 16) = bv[it];
            }
            __syncthreads();
            #pragma unroll
            for (int ks = 0; ks < 2; ++ks) {
                half8 af[2], bf[2];
                #pragma unroll
                for (int i = 0; i < 2; ++i)
                    af[i] = *(const half8*)(Asm +
                            (i * 16 + lane16) * LDA + s * 128 + ks * 64 + quad * 16);
                #pragma unroll
                for (int j = 0; j < 2; ++j)
                    bf[j] = *(const half8*)(Bs +
                            (wc * 32 + j * 16 + lane16) * LDKB + ks * 64 + quad * 16);
                #pragma unroll
                for (int i = 0; i < 2; ++i)
                    #pragma unroll
                    for (int j = 0; j < 2; ++j)
                        acc[i][j] = __builtin_amdgcn_mfma_f32_16x16x32_f16(
                            af[i], bf[j], acc[i][j], 0, 0, 0);
            }
        }

        // epilogue (R10/R11 datapath); C/D layout: col=lane&15, row=quad*4+reg
        #pragma unroll
        for (int i = 0; i < 2; ++i) {
            #pragma unroll
            for (int r = 0; r < 4; ++r) {
                Top2 t; t.s1 = -3.4e38f; t.i1 = 0x7fffffff;
                        t.s2 = -3.4e38f; t.i2 = 0x7fffffff;
                #pragma unroll
                for (int j = 0; j < 2; ++j) {
                    float sv = acc[i][j][r] - hc[j];
                    int col = n0 + wc * 32 + j * 16 + lane16;
                    if (better(sv, col, t.s1, t.i1)) {
                        t.s2 = t.s1; t.i2 = t.i1; t.s1 = sv; t.i1 = col;
                    } else if (better(sv, col, t.s2, t.i2)) {
                        t.s2 = sv; t.i2 = col;
                    }
                }
                #pragma unroll
                for (int m = 1; m < 16; m <<= 1) {
                    Top2 o;
                    o.s1 = __shfl_xor(t.s1, m); o.i1 = __shfl_xor(t.i1, m);
                    o.s2 = __shfl_xor(t.s2, m); o.i2 = __shfl_xor(t.i2, m);
                    t = merge2(t, o);
                }
                if (lane16 == 0) {
                    int rl = i * 16 + quad * 4 + r;   // 0..31
                    topbuf[rl * 4 + wc] =
                        make_float4(t.s1, __int_as_float(t.i1),
                                    t.s2, __int_as_float(t.i2));
                }
            }
        }
        __syncthreads();
        if (tid < 32) {
            float4 rv = rowtop[tid];
            Top2 t{rv.x, __float_as_int(rv.y), rv.z, __float_as_int(rv.w)};
            #pragma unroll
            for (int w = 0; w < 4; ++w) {
                float4 e = topbuf[tid * 4 + w];
                Top2 o{e.x, __float_as_int(e.y), e.z, __float_as_int(e.w)};
                t = merge2(t, o);
            }
            if ((g & 7) == 7) {
                // flush this 1024-col super-group's top2 -> part, reinit
                part[(size_t)(m0 + tid) * 8 + (g >> 3)] =
                    make_float4(t.s1, __int_as_float(t.i1),
                                t.s2, __int_as_float(t.i2));
                rowtop[tid] = make_float4(-3.4e38f, __int_as_float(0x7fffffff),
                                          -3.4e38f, __int_as_float(0x7fffffff));
            } else {
                rowtop[tid] = make_float4(t.s1, __int_as_float(t.i1),
                                          t.s2, __int_as_float(t.i2));
            }
        }
        __syncthreads();
    }
}

// ---- 4. resolve: merge 8 partials/row, fp64-refine near-ties (R4-proven) ----
__global__ __launch_bounds__(256) void resolve(const float4* __restrict__ part,
                                               const float* __restrict__ gr,
                                               const float* __restrict__ gi,
                                               const float* __restrict__ cb,
                                               int* __restrict__ idx) {
    const int row = blockIdx.x * 256 + threadIdx.x;   // grid 128
    float4 e[8];
    #pragma unroll
    for (int j = 0; j < 8; ++j) e[j] = part[(size_t)row * 8 + j];
    Top2 t{-3.4e38f, 0x7fffffff, -3.4e38f, 0x7fffffff};
    #pragma unroll
    for (int j = 0; j < 8; ++j) {
        Top2 o{e[j].x, __float_as_int(e[j].y), e[j].z, __float_as_int(e[j].w)};
        t = merge2(t, o);
    }
    int best = t.i1;
    const float MARGIN = 0.12f;   // ~7.7 sigma of f16-screen score-diff noise
    if (t.s1 - t.s2 < MARGIN) {
        double bd = 1e300; int bi = 0x7fffffff;
        float cut = t.s1 - MARGIN;
        const float* zr = gr + (size_t)row * 128;
        const float* zi = gi + (size_t)row * 128;
        #pragma unroll
        for (int j = 0; j < 8; ++j) {
            #pragma unroll
            for (int c = 0; c < 2; ++c) {
                float sv = c ? e[j].z : e[j].x;
                int   ci = __float_as_int(c ? e[j].w : e[j].y);
                if (sv >= cut && (unsigned)ci < 8192u) {   // clamp: no wild reads
                    const float* crow = cb + (size_t)ci * 256;
                    double d = 0.0;
                    for (int k = 0; k < 128; ++k) {
                        double a = (double)zr[k] - (double)crow[k];
                        double b = (double)zi[k] - (double)crow[128 + k];
                        d += a * a + b * b;
                    }
                    if (d < bd || (d == bd && ci < bi)) { bd = d; bi = ci; }
                }
            }
        }
        if ((unsigned)bi < 8192u) best = bi;
    }
    idx[row] = ((unsigned)best < 8192u) ? best : 0;
}

// ---- 5a. zero the vq accumulator ----
__global__ void zero_vq(float* __restrict__ out, size_t vq_off) {
    out[vq_off] = 0.f;
}

// ---- 5b. gather + proposal(REAL part only) + salience + vq (one wave/row) ----
__global__ __launch_bounds__(256) void gather_epi(const int* __restrict__ idx,
                                                  const float* __restrict__ gr,
                                                  const float* __restrict__ gi,
                                                  const float* __restrict__ cb,
                                                  const float* __restrict__ salw,
                                                  const float* __restrict__ salb,
                                                  float* __restrict__ out,
                                                  size_t sal_off, size_t vq_off) {
    const int wave = threadIdx.x >> 6, lane = threadIdx.x & 63;
    const int row = blockIdx.x * 4 + wave;
    int id = idx[row];
    if ((unsigned)id >= 8192u) id = 0;   // clamp: no wild reads

    float4 c4 = ((const float4*)(cb + (size_t)id * 256))[lane];
    float4 z4 = (lane < 32) ? ((const float4*)(gr + (size_t)row * 128))[lane]
                            : ((const float4*)(gi + (size_t)row * 128))[lane - 32];

    float dx = c4.x - z4.x, dy = c4.y - z4.y, dz = c4.z - z4.z, dw = c4.w - z4.w;
    float vq = dx * dx + dy * dy + dz * dz + dw * dw;
    float4 w4 = ((const float4*)salw)[lane];
    float sal = c4.x * w4.x + c4.y * w4.y + c4.z * w4.z + c4.w * w4.w;
    #pragma unroll
    for (int m = 1; m < 64; m <<= 1) {
        vq  += __shfl_xor(vq, m);
        sal += __shfl_xor(sal, m);
    }

    // proposal: real part only — lanes 0..31 hold c[0..128) as float4s
    if (lane < 32 && (size_t)(row + 1) * 128 <= sal_off) {
        float4* op = (float4*)(out + (size_t)row * 128);
        op[lane] = c4;
    }
    if (lane == 0 && sal_off + row < vq_off)
        out[sal_off + row] = sal + salb[0];

    __shared__ float vqs[4];
    if (lane == 0) vqs[wave] = vq;
    __syncthreads();
    if (threadIdx.x == 0) {
        float p = (vqs[0] + vqs[1] + vqs[2] + vqs[3]) * (1.25f / 8388608.f);
        atomicAdd(out + vq_off, p);
    }
}

extern "C" void kernel_launch(void* const* d_in, const int* in_sizes, int n_in,
                              void* d_out, int out_size, void* d_ws, size_t ws_size,
                              hipStream_t stream) {
    const float* gr = (const float*)d_in[0];   // gw_real  [8,4096,128]
    const float* gi = (const float*)d_in[1];   // gw_imag  [8,4096,128]
    const float* cb = (const float*)d_in[2];   // codebook [8192,256]
    const float* sw = (const float*)d_in[3];   // sal_w    [1,256]
    const float* sb = (const float*)d_in[4];   // sal_b    [1]
    float* out = (float*)d_out;

    // Output offsets (out_size = 4,227,073 floats:
    // proposal-real 4,194,304 | salience 32,768 | vq_loss 1).
    size_t vq_off  = (size_t)out_size - 1;
    size_t sal_off = (size_t)out_size - 1 - 32768;

    char* base = (char*)d_ws;
    int*  idxb = (int*)(base + IDX_OFF);
    _Float16* A    = (_Float16*)(base + A_OFF);
    _Float16* Bq   = (_Float16*)(base + B_OFF);
    float*    cn   = (float*)   (base + CN_OFF);
    float4*   part = (float4*)  (base + PART_OFF);

    prep_z<<<8192, 256, 0, stream>>>(gr, gi, A);
    prep_c<<<8192, 64, 0, stream>>>(cb, Bq, cn);
    gemm_argmin<<<1024, 256, 0, stream>>>(A, Bq, cn, part);
    resolve<<<128, 256, 0, stream>>>(part, gr, gi, cb, idxb);
    zero_vq<<<1, 1, 0, stream>>>(out, vq_off);
    gather_epi<<<8192, 256, 0, stream>>>(idxb, gr, gi, cb, sw, sb, out,
                                         sal_off, vq_off);
}

// Round 13
// 2439.695 us; speedup vs baseline: 1.0002x; 1.0002x over previous
//
#include <hip/hip_runtime.h>
#include <stdint.h>

// Problem constants
#define MROWS 32768      // B*S = 8*4096
#define KD    256        // 2*DIM
#define VOCABN 8192

typedef _Float16 half8  __attribute__((ext_vector_type(8)));
typedef _Float16 half4v __attribute__((ext_vector_type(4)));
typedef float  floatx4  __attribute__((ext_vector_type(4)));

#define LDA 528    // A LDS row stride: 512 B data + 16 B pad
#define LDKB 144   // B LDS row stride: 128 B data + 16 B pad (R4/R10-proven)

// scratch layout (byte offsets within d_ws; ws_size >= WS_NEED verified R3/R4)
#define A_OFF     0u          // f16 z  [32768][256]  = 16,777,216 B
#define B_OFF     16777216u   // f16 cb [8192][256]   =  4,194,304 B
#define CN_OFF    20971520u   // f32 0.5*||c||^2 [8192] = 32,768 B
#define PART_OFF  21004288u   // float4 top2 [32768][8] = 4,194,304 B
#define IDX_OFF   25198592u   // int idx [32768] = 131,072 B
#define WS_NEED   25329664u

// ---- top-2 (max sigma) with smaller-index tie-break ----
struct Top2 { float s1; int i1; float s2; int i2; };

__device__ __forceinline__ bool better(float sa, int ia, float sb, int ib) {
    return (sa > sb) || (sa == sb && ia < ib);
}
__device__ __forceinline__ Top2 merge2(const Top2& a, const Top2& b) {
    Top2 r;
    if (better(b.s1, b.i1, a.s1, a.i1)) {
        r.s1 = b.s1; r.i1 = b.i1;
        if (better(a.s1, a.i1, b.s2, b.i2)) { r.s2 = a.s1; r.i2 = a.i1; }
        else                                { r.s2 = b.s2; r.i2 = b.i2; }
    } else {
        r.s1 = a.s1; r.i1 = a.i1;
        if (better(b.s1, b.i1, a.s2, a.i2)) { r.s2 = b.s1; r.i2 = b.i1; }
        else                                { r.s2 = a.s2; r.i2 = a.i2; }
    }
    return r;
}

// ---- 1. z = concat(real,imag) as f16 [32768][256] ----
__global__ __launch_bounds__(256) void prep_z(const float* __restrict__ gr,
                                              const float* __restrict__ gi,
                                              _Float16* __restrict__ A) {
    int t = blockIdx.x * 256 + threadIdx.x;     // 4 elements/thread
    int base = t * 4;
    int m = base >> 8;
    int k = base & 255;
    float4 v;
    if (k < 128) v = *(const float4*)(gr + (size_t)m * 128 + k);
    else         v = *(const float4*)(gi + (size_t)m * 128 + (k - 128));
    half4v h;
    h[0] = (_Float16)v.x; h[1] = (_Float16)v.y;
    h[2] = (_Float16)v.z; h[3] = (_Float16)v.w;
    *(half4v*)(A + base) = h;
}

// ---- 2. codebook f16 [8192][256] + 0.5*||c||^2 fp32 ----
__global__ __launch_bounds__(64) void prep_c(const float* __restrict__ cb,
                                             _Float16* __restrict__ B,
                                             float* __restrict__ cnorm) {
    int v = blockIdx.x;
    int lane = threadIdx.x;                    // 0..63, 4 floats each
    float4 c = ((const float4*)(cb + (size_t)v * 256))[lane];
    half4v h;
    h[0] = (_Float16)c.x; h[1] = (_Float16)c.y;
    h[2] = (_Float16)c.z; h[3] = (_Float16)c.w;
    ((half4v*)(B + (size_t)v * 256))[lane] = h;
    float s = c.x * c.x + c.y * c.y + c.z * c.z + c.w * c.w;
    #pragma unroll
    for (int m = 32; m; m >>= 1) s += __shfl_xor(s, m);
    if (lane == 0) cnorm[v] = 0.5f * s;
}

// ---- 3. f16 GEMM + per-row top-2 argmax(sigma) ----
// R11/R12 post-mortem: compiler targeted ~52 arch VGPRs (ignoring the 4
// blocks/CU LDS cap) and spilled the B staging regs -> 1.5 GB scratch
// traffic = the whole 2.36 ms (685 GB/s * 2.3 ms closes exactly).
// __launch_bounds__(256, 1) pins the budget at 1 wave/EU (512 VGPRs) so
// nothing spills; occupancy stays LDS-capped at 4 blocks/CU. Source is
// otherwise byte-identical to the R12-passing kernel.
__global__ __launch_bounds__(256, 1) void gemm_argmin(const _Float16* __restrict__ A,
                                                      const _Float16* __restrict__ B,
                                                      const float* __restrict__ cnorm,
                                                      float4* __restrict__ part) {
    __shared__ __align__(16) char   Asm[32 * LDA];     // 16,896 B
    __shared__ __align__(16) char   Bs[128 * LDKB];    // 18,432 B
    __shared__ __align__(16) float4 topbuf[128];       // [32 rows][4 col-waves]
    __shared__ __align__(16) float4 rowtop[32];        // per-row running top2

    const int tid = threadIdx.x;
    const int m0 = blockIdx.x * 32;
    const int wave = tid >> 6, lane = tid & 63;
    const int wc = wave;                               // 1x4: 32 rows x 32 cols/wave
    const int lane16 = lane & 15, quad = lane >> 4;

    // one-time A-tile stage: 32 rows x 512 B; 8 threads/row, 64 B each
    {
        int r = tid >> 3, qo = (tid & 7) * 32;         // f16 element offset
        const _Float16* ag = A + (size_t)(m0 + r) * 256 + qo;
        char* al = Asm + r * LDA + qo * 2;
        uint4 tmp[4];
        #pragma unroll
        for (int i = 0; i < 4; ++i) tmp[i] = *(const uint4*)(ag + i * 8);
        #pragma unroll
        for (int i = 0; i < 4; ++i) *(uint4*)(al + i * 16) = tmp[i];
    }
    if (tid < 32)
        rowtop[tid] = make_float4(-3.4e38f, __int_as_float(0x7fffffff),
                                  -3.4e38f, __int_as_float(0x7fffffff));

    for (int g = 0; g < 64; ++g) {
        const int n0 = g * 128;

        float hc[2];
        #pragma unroll
        for (int j = 0; j < 2; ++j)
            hc[j] = cnorm[n0 + wc * 32 + j * 16 + lane16];

        floatx4 acc[2][2];
        #pragma unroll
        for (int i = 0; i < 2; ++i)
            #pragma unroll
            for (int j = 0; j < 2; ++j)
                acc[i][j] = (floatx4){0.f, 0.f, 0.f, 0.f};

        for (int s = 0; s < 4; ++s) {
            const int k0 = s * 64;
            // B tile: 128 rows x 64 f16 = 1024 16B chunks; 4/thread (R10 order:
            // loads issued pre-barrier, overlap prior stage's MFMA tail)
            uint4 bv[4];
            #pragma unroll
            for (int it = 0; it < 4; ++it) {
                int c = it * 256 + tid;        // 0..1023
                int r = c >> 3, ci = c & 7;
                bv[it] = *(const uint4*)(B + (size_t)(n0 + r) * 256 + k0 + ci * 8);
            }
            __syncthreads();   // prior stage's Bs reads done (covers A/rowtop at g0s0)
            #pragma unroll
            for (int it = 0; it < 4; ++it) {
                int c = it * 256 + tid;
                *(uint4*)(Bs + (c >> 3) * LDKB + (c & 7) * 16) = bv[it];
            }
            __syncthreads();
            #pragma unroll
            for (int ks = 0; ks < 2; ++ks) {
                half8 af[2], bf[2];
                #pragma unroll
                for (int i = 0; i < 2; ++i)
                    af[i] = *(const half8*)(Asm +
                            (i * 16 + lane16) * LDA + s * 128 + ks * 64 + quad * 16);
                #pragma unroll
                for (int j = 0; j < 2; ++j)
                    bf[j] = *(const half8*)(Bs +
                            (wc * 32 + j * 16 + lane16) * LDKB + ks * 64 + quad * 16);
                #pragma unroll
                for (int i = 0; i < 2; ++i)
                    #pragma unroll
                    for (int j = 0; j < 2; ++j)
                        acc[i][j] = __builtin_amdgcn_mfma_f32_16x16x32_f16(
                            af[i], bf[j], acc[i][j], 0, 0, 0);
            }
        }

        // epilogue (R10/R11 datapath); C/D layout: col=lane&15, row=quad*4+reg
        #pragma unroll
        for (int i = 0; i < 2; ++i) {
            #pragma unroll
            for (int r = 0; r < 4; ++r) {
                Top2 t; t.s1 = -3.4e38f; t.i1 = 0x7fffffff;
                        t.s2 = -3.4e38f; t.i2 = 0x7fffffff;
                #pragma unroll
                for (int j = 0; j < 2; ++j) {
                    float sv = acc[i][j][r] - hc[j];
                    int col = n0 + wc * 32 + j * 16 + lane16;
                    if (better(sv, col, t.s1, t.i1)) {
                        t.s2 = t.s1; t.i2 = t.i1; t.s1 = sv; t.i1 = col;
                    } else if (better(sv, col, t.s2, t.i2)) {
                        t.s2 = sv; t.i2 = col;
                    }
                }
                #pragma unroll
                for (int m = 1; m < 16; m <<= 1) {
                    Top2 o;
                    o.s1 = __shfl_xor(t.s1, m); o.i1 = __shfl_xor(t.i1, m);
                    o.s2 = __shfl_xor(t.s2, m); o.i2 = __shfl_xor(t.i2, m);
                    t = merge2(t, o);
                }
                if (lane16 == 0) {
                    int rl = i * 16 + quad * 4 + r;   // 0..31
                    topbuf[rl * 4 + wc] =
                        make_float4(t.s1, __int_as_float(t.i1),
                                    t.s2, __int_as_float(t.i2));
                }
            }
        }
        __syncthreads();
        if (tid < 32) {
            float4 rv = rowtop[tid];
            Top2 t{rv.x, __float_as_int(rv.y), rv.z, __float_as_int(rv.w)};
            #pragma unroll
            for (int w = 0; w < 4; ++w) {
                float4 e = topbuf[tid * 4 + w];
                Top2 o{e.x, __float_as_int(e.y), e.z, __float_as_int(e.w)};
                t = merge2(t, o);
            }
            if ((g & 7) == 7) {
                // flush this 1024-col super-group's top2 -> part, reinit
                part[(size_t)(m0 + tid) * 8 + (g >> 3)] =
                    make_float4(t.s1, __int_as_float(t.i1),
                                t.s2, __int_as_float(t.i2));
                rowtop[tid] = make_float4(-3.4e38f, __int_as_float(0x7fffffff),
                                          -3.4e38f, __int_as_float(0x7fffffff));
            } else {
                rowtop[tid] = make_float4(t.s1, __int_as_float(t.i1),
                                          t.s2, __int_as_float(t.i2));
            }
        }
        __syncthreads();
    }
}

// ---- 4. resolve: merge 8 partials/row, fp64-refine near-ties (R4-proven) ----
__global__ __launch_bounds__(256) void resolve(const float4* __restrict__ part,
                                               const float* __restrict__ gr,
                                               const float* __restrict__ gi,
                                               const float* __restrict__ cb,
                                               int* __restrict__ idx) {
    const int row = blockIdx.x * 256 + threadIdx.x;   // grid 128
    float4 e[8];
    #pragma unroll
    for (int j = 0; j < 8; ++j) e[j] = part[(size_t)row * 8 + j];
    Top2 t{-3.4e38f, 0x7fffffff, -3.4e38f, 0x7fffffff};
    #pragma unroll
    for (int j = 0; j < 8; ++j) {
        Top2 o{e[j].x, __float_as_int(e[j].y), e[j].z, __float_as_int(e[j].w)};
        t = merge2(t, o);
    }
    int best = t.i1;
    const float MARGIN = 0.12f;   // ~7.7 sigma of f16-screen score-diff noise
    if (t.s1 - t.s2 < MARGIN) {
        double bd = 1e300; int bi = 0x7fffffff;
        float cut = t.s1 - MARGIN;
        const float* zr = gr + (size_t)row * 128;
        const float* zi = gi + (size_t)row * 128;
        #pragma unroll
        for (int j = 0; j < 8; ++j) {
            #pragma unroll
            for (int c = 0; c < 2; ++c) {
                float sv = c ? e[j].z : e[j].x;
                int   ci = __float_as_int(c ? e[j].w : e[j].y);
                if (sv >= cut && (unsigned)ci < 8192u) {   // clamp: no wild reads
                    const float* crow = cb + (size_t)ci * 256;
                    double d = 0.0;
                    for (int k = 0; k < 128; ++k) {
                        double a = (double)zr[k] - (double)crow[k];
                        double b = (double)zi[k] - (double)crow[128 + k];
                        d += a * a + b * b;
                    }
                    if (d < bd || (d == bd && ci < bi)) { bd = d; bi = ci; }
                }
            }
        }
        if ((unsigned)bi < 8192u) best = bi;
    }
    idx[row] = ((unsigned)best < 8192u) ? best : 0;
}

// ---- 5a. zero the vq accumulator ----
__global__ void zero_vq(float* __restrict__ out, size_t vq_off) {
    out[vq_off] = 0.f;
}

// ---- 5b. gather + proposal(REAL part only) + salience + vq (one wave/row) ----
__global__ __launch_bounds__(256) void gather_epi(const int* __restrict__ idx,
                                                  const float* __restrict__ gr,
                                                  const float* __restrict__ gi,
                                                  const float* __restrict__ cb,
                                                  const float* __restrict__ salw,
                                                  const float* __restrict__ salb,
                                                  float* __restrict__ out,
                                                  size_t sal_off, size_t vq_off) {
    const int wave = threadIdx.x >> 6, lane = threadIdx.x & 63;
    const int row = blockIdx.x * 4 + wave;
    int id = idx[row];
    if ((unsigned)id >= 8192u) id = 0;   // clamp: no wild reads

    float4 c4 = ((const float4*)(cb + (size_t)id * 256))[lane];
    float4 z4 = (lane < 32) ? ((const float4*)(gr + (size_t)row * 128))[lane]
                            : ((const float4*)(gi + (size_t)row * 128))[lane - 32];

    float dx = c4.x - z4.x, dy = c4.y - z4.y, dz = c4.z - z4.z, dw = c4.w - z4.w;
    float vq = dx * dx + dy * dy + dz * dz + dw * dw;
    float4 w4 = ((const float4*)salw)[lane];
    float sal = c4.x * w4.x + c4.y * w4.y + c4.z * w4.z + c4.w * w4.w;
    #pragma unroll
    for (int m = 1; m < 64; m <<= 1) {
        vq  += __shfl_xor(vq, m);
        sal += __shfl_xor(sal, m);
    }

    // proposal: real part only — lanes 0..31 hold c[0..128) as float4s
    if (lane < 32 && (size_t)(row + 1) * 128 <= sal_off) {
        float4* op = (float4*)(out + (size_t)row * 128);
        op[lane] = c4;
    }
    if (lane == 0 && sal_off + row < vq_off)
        out[sal_off + row] = sal + salb[0];

    __shared__ float vqs[4];
    if (lane == 0) vqs[wave] = vq;
    __syncthreads();
    if (threadIdx.x == 0) {
        float p = (vqs[0] + vqs[1] + vqs[2] + vqs[3]) * (1.25f / 8388608.f);
        atomicAdd(out + vq_off, p);
    }
}

extern "C" void kernel_launch(void* const* d_in, const int* in_sizes, int n_in,
                              void* d_out, int out_size, void* d_ws, size_t ws_size,
                              hipStream_t stream) {
    const float* gr = (const float*)d_in[0];   // gw_real  [8,4096,128]
    const float* gi = (const float*)d_in[1];   // gw_imag  [8,4096,128]
    const float* cb = (const float*)d_in[2];   // codebook [8192,256]
    const float* sw = (const float*)d_in[3];   // sal_w    [1,256]
    const float* sb = (const float*)d_in[4];   // sal_b    [1]
    float* out = (float*)d_out;

    // Output offsets (out_size = 4,227,073 floats:
    // proposal-real 4,194,304 | salience 32,768 | vq_loss 1).
    size_t vq_off  = (size_t)out_size - 1;
    size_t sal_off = (size_t)out_size - 1 - 32768;

    char* base = (char*)d_ws;
    int*  idxb = (int*)(base + IDX_OFF);
    _Float16* A    = (_Float16*)(base + A_OFF);
    _Float16* Bq   = (_Float16*)(base + B_OFF);
    float*    cn   = (float*)   (base + CN_OFF);
    float4*   part = (float4*)  (base + PART_OFF);

    prep_z<<<8192, 256, 0, stream>>>(gr, gi, A);
    prep_c<<<8192, 64, 0, stream>>>(cb, Bq, cn);
    gemm_argmin<<<1024, 256, 0, stream>>>(A, Bq, cn, part);
    resolve<<<128, 256, 0, stream>>>(part, gr, gi, cb, idxb);
    zero_vq<<<1, 1, 0, stream>>>(out, vq_off);
    gather_epi<<<8192, 256, 0, stream>>>(idxb, gr, gi, cb, sw, sb, out,
                                         sal_off, vq_off);
}

// Round 14
// 964.163 us; speedup vs baseline: 2.5310x; 2.5304x over previous
//
#include <hip/hip_runtime.h>
#include <stdint.h>

// Problem constants
#define MROWS 32768      // B*S = 8*4096
#define KD    256        // 2*DIM
#define VOCABN 8192

typedef _Float16 half8  __attribute__((ext_vector_type(8)));
typedef _Float16 half4v __attribute__((ext_vector_type(4)));
typedef float  floatx4  __attribute__((ext_vector_type(4)));

#define LDA 528    // A LDS row stride: 512 B data + 16 B pad
#define LDKB 144   // B LDS row stride: 128 B data + 16 B pad (R4/R10-proven)

// scratch layout (byte offsets within d_ws; ws_size >= WS_NEED verified R3/R4)
#define A_OFF     0u          // f16 z  [32768][256]  = 16,777,216 B
#define B_OFF     16777216u   // f16 cb [8192][256]   =  4,194,304 B
#define CN_OFF    20971520u   // f32 0.5*||c||^2 [8192] = 32,768 B
#define PART_OFF  21004288u   // float4 top2 [32768][8] = 4,194,304 B
#define IDX_OFF   25198592u   // int idx [32768] = 131,072 B
#define WS_NEED   25329664u

// ---- top-2 (max sigma) with smaller-index tie-break ----
struct Top2 { float s1; int i1; float s2; int i2; };

__device__ __forceinline__ bool better(float sa, int ia, float sb, int ib) {
    return (sa > sb) || (sa == sb && ia < ib);
}
__device__ __forceinline__ Top2 merge2(const Top2& a, const Top2& b) {
    Top2 r;
    if (better(b.s1, b.i1, a.s1, a.i1)) {
        r.s1 = b.s1; r.i1 = b.i1;
        if (better(a.s1, a.i1, b.s2, b.i2)) { r.s2 = a.s1; r.i2 = a.i1; }
        else                                { r.s2 = b.s2; r.i2 = b.i2; }
    } else {
        r.s1 = a.s1; r.i1 = a.i1;
        if (better(b.s1, b.i1, a.s2, a.i2)) { r.s2 = b.s1; r.i2 = b.i1; }
        else                                { r.s2 = a.s2; r.i2 = a.i2; }
    }
    return r;
}

// ---- 1. z = concat(real,imag) as f16 [32768][256] ----
__global__ __launch_bounds__(256) void prep_z(const float* __restrict__ gr,
                                              const float* __restrict__ gi,
                                              _Float16* __restrict__ A) {
    int t = blockIdx.x * 256 + threadIdx.x;     // 4 elements/thread
    int base = t * 4;
    int m = base >> 8;
    int k = base & 255;
    float4 v;
    if (k < 128) v = *(const float4*)(gr + (size_t)m * 128 + k);
    else         v = *(const float4*)(gi + (size_t)m * 128 + (k - 128));
    half4v h;
    h[0] = (_Float16)v.x; h[1] = (_Float16)v.y;
    h[2] = (_Float16)v.z; h[3] = (_Float16)v.w;
    *(half4v*)(A + base) = h;
}

// ---- 2. codebook f16 [8192][256] + 0.5*||c||^2 fp32 ----
__global__ __launch_bounds__(64) void prep_c(const float* __restrict__ cb,
                                             _Float16* __restrict__ B,
                                             float* __restrict__ cnorm) {
    int v = blockIdx.x;
    int lane = threadIdx.x;                    // 0..63, 4 floats each
    float4 c = ((const float4*)(cb + (size_t)v * 256))[lane];
    half4v h;
    h[0] = (_Float16)c.x; h[1] = (_Float16)c.y;
    h[2] = (_Float16)c.z; h[3] = (_Float16)c.w;
    ((half4v*)(B + (size_t)v * 256))[lane] = h;
    float s = c.x * c.x + c.y * c.y + c.z * c.z + c.w * c.w;
    #pragma unroll
    for (int m = 32; m; m >>= 1) s += __shfl_xor(s, m);
    if (lane == 0) cnorm[v] = 0.5f * s;
}

// ---- 3. f16 GEMM + per-row top-2 argmax(sigma) ----
// R13 post-mortem: R10 (this kernel's base) is LDS-pipe-bound: per wave per g,
// 48 ds_read_b128 (A frags re-read every g) + 128 ds_bpermute (per-g 16-lane
// butterfly) + 16 staging writes ~ 1300 LDS-pipe cyc -> ~300 us/CU floor.
// Two cuts, all else byte-identical to R10 (grid 512, BM=64, 2x2 waves,
// VGPR-round-trip staging): (1) A-fragments preloaded ONCE into registers
// (s-loop unrolled, af[i][s][ks] compile-time indexed); (2) per-lane register
// Top2 across 8 g, butterfly/topbuf/part flush only at g&7==7 (same 1024-col
// candidate granularity, same part[32768][8] layout).
__global__ __launch_bounds__(256) void gemm_argmin(const _Float16* __restrict__ A,
                                                   const _Float16* __restrict__ B,
                                                   const float* __restrict__ cnorm,
                                                   float4* __restrict__ part) {
    __shared__ __align__(16) char   Asm[64 * LDA];     // 33,792 B
    __shared__ __align__(16) char   Bs[128 * LDKB];    // 18,432 B
    __shared__ __align__(16) float4 topbuf[128];       // [64 rows][2 col-halves]

    const int tid = threadIdx.x;
    const int m0 = blockIdx.x * 64;
    const int wave = tid >> 6, lane = tid & 63;
    const int wr = wave >> 1, wc = wave & 1;           // 2x2: 32 rows x 64 cols
    const int lane16 = lane & 15, quad = lane >> 4;

    // one-time A-tile stage: 64 rows x 512 B; 4 threads/row, 128 B each
    {
        int r = tid >> 2, qo = (tid & 3) * 64;         // f16 element offset
        const _Float16* ag = A + (size_t)(m0 + r) * 256 + qo;
        char* al = Asm + r * LDA + qo * 2;
        uint4 tmp[8];
        #pragma unroll
        for (int i = 0; i < 8; ++i) tmp[i] = *(const uint4*)(ag + i * 8);
        #pragma unroll
        for (int i = 0; i < 8; ++i) *(uint4*)(al + i * 16) = tmp[i];
    }
    __syncthreads();

    // A-fragments into registers ONCE (g-invariant); all indices compile-time
    half8 af[2][4][2];   // [i][s][ks]
    #pragma unroll
    for (int i = 0; i < 2; ++i)
        #pragma unroll
        for (int s = 0; s < 4; ++s)
            #pragma unroll
            for (int ks = 0; ks < 2; ++ks)
                af[i][s][ks] = *(const half8*)(Asm +
                    (wr * 32 + i * 16 + lane16) * LDA + s * 128 + ks * 64 + quad * 16);

    // per-lane running top-2 (registers), flushed every 8 g
    Top2 t2[2][4];
    #pragma unroll
    for (int i = 0; i < 2; ++i)
        #pragma unroll
        for (int r = 0; r < 4; ++r)
            t2[i][r] = Top2{-3.4e38f, 0x7fffffff, -3.4e38f, 0x7fffffff};

    for (int g = 0; g < 64; ++g) {
        const int n0 = g * 128;

        float hc[4];
        #pragma unroll
        for (int j = 0; j < 4; ++j)
            hc[j] = cnorm[n0 + wc * 64 + j * 16 + lane16];

        floatx4 acc[2][4];
        #pragma unroll
        for (int i = 0; i < 2; ++i)
            #pragma unroll
            for (int j = 0; j < 4; ++j)
                acc[i][j] = (floatx4){0.f, 0.f, 0.f, 0.f};

        #pragma unroll
        for (int s = 0; s < 4; ++s) {
            const int k0 = s * 64;
            // B tile: 128 rows x 64 f16 = 1024 16B chunks; 4/thread (R10 order)
            uint4 bv[4];
            #pragma unroll
            for (int it = 0; it < 4; ++it) {
                int c = it * 256 + tid;        // 0..1023
                int r = c >> 3, ci = c & 7;
                bv[it] = *(const uint4*)(B + (size_t)(n0 + r) * 256 + k0 + ci * 8);
            }
            __syncthreads();   // prior stage's Bs reads done
            #pragma unroll
            for (int it = 0; it < 4; ++it) {
                int c = it * 256 + tid;
                *(uint4*)(Bs + (c >> 3) * LDKB + (c & 7) * 16) = bv[it];
            }
            __syncthreads();
            #pragma unroll
            for (int ks = 0; ks < 2; ++ks) {
                half8 bf[4];
                #pragma unroll
                for (int j = 0; j < 4; ++j)
                    bf[j] = *(const half8*)(Bs +
                            (wc * 64 + j * 16 + lane16) * LDKB + ks * 64 + quad * 16);
                #pragma unroll
                for (int i = 0; i < 2; ++i)
                    #pragma unroll
                    for (int j = 0; j < 4; ++j)
                        acc[i][j] = __builtin_amdgcn_mfma_f32_16x16x32_f16(
                            af[i][s][ks], bf[j], acc[i][j], 0, 0, 0);
            }
        }

        // per-g top-2 update (registers only; C/D: col=lane&15, row=quad*4+reg)
        #pragma unroll
        for (int i = 0; i < 2; ++i)
            #pragma unroll
            for (int r = 0; r < 4; ++r) {
                #pragma unroll
                for (int j = 0; j < 4; ++j) {
                    float sv = acc[i][j][r] - hc[j];
                    int col = n0 + wc * 64 + j * 16 + lane16;
                    Top2& t = t2[i][r];
                    if (better(sv, col, t.s1, t.i1)) {
                        t.s2 = t.s1; t.i2 = t.i1; t.s1 = sv; t.i1 = col;
                    } else if (better(sv, col, t.s2, t.i2)) {
                        t.s2 = sv; t.i2 = col;
                    }
                }
            }

        // flush every 8 g: butterfly + cross-wave merge + part write
        if ((g & 7) == 7) {
            const int slot = g >> 3;
            #pragma unroll
            for (int i = 0; i < 2; ++i)
                #pragma unroll
                for (int r = 0; r < 4; ++r) {
                    Top2 t = t2[i][r];
                    #pragma unroll
                    for (int m = 1; m < 16; m <<= 1) {
                        Top2 o;
                        o.s1 = __shfl_xor(t.s1, m); o.i1 = __shfl_xor(t.i1, m);
                        o.s2 = __shfl_xor(t.s2, m); o.i2 = __shfl_xor(t.i2, m);
                        t = merge2(t, o);
                    }
                    if (lane16 == 0) {
                        int rl = wr * 32 + i * 16 + quad * 4 + r;   // 0..63
                        topbuf[rl * 2 + wc] =
                            make_float4(t.s1, __int_as_float(t.i1),
                                        t.s2, __int_as_float(t.i2));
                    }
                    t2[i][r] = Top2{-3.4e38f, 0x7fffffff, -3.4e38f, 0x7fffffff};
                }
            __syncthreads();
            if (tid < 64) {
                float4 e0 = topbuf[tid * 2 + 0], e1 = topbuf[tid * 2 + 1];
                Top2 a{e0.x, __float_as_int(e0.y), e0.z, __float_as_int(e0.w)};
                Top2 b{e1.x, __float_as_int(e1.y), e1.z, __float_as_int(e1.w)};
                Top2 t = merge2(a, b);
                part[(size_t)(m0 + tid) * 8 + slot] =
                    make_float4(t.s1, __int_as_float(t.i1),
                                t.s2, __int_as_float(t.i2));
            }
            __syncthreads();   // topbuf reusable next flush
        }
    }
}

// ---- 4. resolve: merge 8 partials/row, fp64-refine near-ties (R4-proven) ----
__global__ __launch_bounds__(256) void resolve(const float4* __restrict__ part,
                                               const float* __restrict__ gr,
                                               const float* __restrict__ gi,
                                               const float* __restrict__ cb,
                                               int* __restrict__ idx) {
    const int row = blockIdx.x * 256 + threadIdx.x;   // grid 128
    float4 e[8];
    #pragma unroll
    for (int j = 0; j < 8; ++j) e[j] = part[(size_t)row * 8 + j];
    Top2 t{-3.4e38f, 0x7fffffff, -3.4e38f, 0x7fffffff};
    #pragma unroll
    for (int j = 0; j < 8; ++j) {
        Top2 o{e[j].x, __float_as_int(e[j].y), e[j].z, __float_as_int(e[j].w)};
        t = merge2(t, o);
    }
    int best = t.i1;
    const float MARGIN = 0.12f;   // ~7.7 sigma of f16-screen score-diff noise
    if (t.s1 - t.s2 < MARGIN) {
        double bd = 1e300; int bi = 0x7fffffff;
        float cut = t.s1 - MARGIN;
        const float* zr = gr + (size_t)row * 128;
        const float* zi = gi + (size_t)row * 128;
        #pragma unroll
        for (int j = 0; j < 8; ++j) {
            #pragma unroll
            for (int c = 0; c < 2; ++c) {
                float sv = c ? e[j].z : e[j].x;
                int   ci = __float_as_int(c ? e[j].w : e[j].y);
                if (sv >= cut && (unsigned)ci < 8192u) {   // clamp: no wild reads
                    const float* crow = cb + (size_t)ci * 256;
                    double d = 0.0;
                    for (int k = 0; k < 128; ++k) {
                        double a = (double)zr[k] - (double)crow[k];
                        double b = (double)zi[k] - (double)crow[128 + k];
                        d += a * a + b * b;
                    }
                    if (d < bd || (d == bd && ci < bi)) { bd = d; bi = ci; }
                }
            }
        }
        if ((unsigned)bi < 8192u) best = bi;
    }
    idx[row] = ((unsigned)best < 8192u) ? best : 0;
}

// ---- 5a. zero the vq accumulator ----
__global__ void zero_vq(float* __restrict__ out, size_t vq_off) {
    out[vq_off] = 0.f;
}

// ---- 5b. gather + proposal(REAL part only) + salience + vq (one wave/row) ----
__global__ __launch_bounds__(256) void gather_epi(const int* __restrict__ idx,
                                                  const float* __restrict__ gr,
                                                  const float* __restrict__ gi,
                                                  const float* __restrict__ cb,
                                                  const float* __restrict__ salw,
                                                  const float* __restrict__ salb,
                                                  float* __restrict__ out,
                                                  size_t sal_off, size_t vq_off) {
    const int wave = threadIdx.x >> 6, lane = threadIdx.x & 63;
    const int row = blockIdx.x * 4 + wave;
    int id = idx[row];
    if ((unsigned)id >= 8192u) id = 0;   // clamp: no wild reads

    float4 c4 = ((const float4*)(cb + (size_t)id * 256))[lane];
    float4 z4 = (lane < 32) ? ((const float4*)(gr + (size_t)row * 128))[lane]
                            : ((const float4*)(gi + (size_t)row * 128))[lane - 32];

    float dx = c4.x - z4.x, dy = c4.y - z4.y, dz = c4.z - z4.z, dw = c4.w - z4.w;
    float vq = dx * dx + dy * dy + dz * dz + dw * dw;
    float4 w4 = ((const float4*)salw)[lane];
    float sal = c4.x * w4.x + c4.y * w4.y + c4.z * w4.z + c4.w * w4.w;
    #pragma unroll
    for (int m = 1; m < 64; m <<= 1) {
        vq  += __shfl_xor(vq, m);
        sal += __shfl_xor(sal, m);
    }

    // proposal: real part only — lanes 0..31 hold c[0..128) as float4s
    if (lane < 32 && (size_t)(row + 1) * 128 <= sal_off) {
        float4* op = (float4*)(out + (size_t)row * 128);
        op[lane] = c4;
    }
    if (lane == 0 && sal_off + row < vq_off)
        out[sal_off + row] = sal + salb[0];

    __shared__ float vqs[4];
    if (lane == 0) vqs[wave] = vq;
    __syncthreads();
    if (threadIdx.x == 0) {
        float p = (vqs[0] + vqs[1] + vqs[2] + vqs[3]) * (1.25f / 8388608.f);
        atomicAdd(out + vq_off, p);
    }
}

extern "C" void kernel_launch(void* const* d_in, const int* in_sizes, int n_in,
                              void* d_out, int out_size, void* d_ws, size_t ws_size,
                              hipStream_t stream) {
    const float* gr = (const float*)d_in[0];   // gw_real  [8,4096,128]
    const float* gi = (const float*)d_in[1];   // gw_imag  [8,4096,128]
    const float* cb = (const float*)d_in[2];   // codebook [8192,256]
    const float* sw = (const float*)d_in[3];   // sal_w    [1,256]
    const float* sb = (const float*)d_in[4];   // sal_b    [1]
    float* out = (float*)d_out;

    // Output offsets (out_size = 4,227,073 floats:
    // proposal-real 4,194,304 | salience 32,768 | vq_loss 1).
    size_t vq_off  = (size_t)out_size - 1;
    size_t sal_off = (size_t)out_size - 1 - 32768;

    char* base = (char*)d_ws;
    int*  idxb = (int*)(base + IDX_OFF);
    _Float16* A    = (_Float16*)(base + A_OFF);
    _Float16* Bq   = (_Float16*)(base + B_OFF);
    float*    cn   = (float*)   (base + CN_OFF);
    float4*   part = (float4*)  (base + PART_OFF);

    prep_z<<<8192, 256, 0, stream>>>(gr, gi, A);
    prep_c<<<8192, 64, 0, stream>>>(cb, Bq, cn);
    gemm_argmin<<<512, 256, 0, stream>>>(A, Bq, cn, part);
    resolve<<<128, 256, 0, stream>>>(part, gr, gi, cb, idxb);
    zero_vq<<<1, 1, 0, stream>>>(out, vq_off);
    gather_epi<<<8192, 256, 0, stream>>>(idxb, gr, gi, cb, sw, sb, out,
                                         sal_off, vq_off);
}

// Round 15
// 813.032 us; speedup vs baseline: 3.0014x; 1.1859x over previous
//
#include <hip/hip_runtime.h>
#include <stdint.h>

// Problem constants
#define MROWS 32768      // B*S = 8*4096
#define KD    256        // 2*DIM
#define VOCABN 8192

typedef _Float16 half8  __attribute__((ext_vector_type(8)));
typedef _Float16 half4v __attribute__((ext_vector_type(4)));
typedef float  floatx4  __attribute__((ext_vector_type(4)));

// scratch layout (byte offsets within d_ws; ws_size >= WS_NEED verified R3/R4)
#define A_OFF     0u          // f16 z  [32768][256]  = 16,777,216 B
#define B_OFF     16777216u   // f16 cb [8192][256]   =  4,194,304 B
#define CN_OFF    20971520u   // f32 0.5*||c||^2 [8192] = 32,768 B
#define PART_OFF  21004288u   // float4 top2 [32768][8] = 4,194,304 B
#define IDX_OFF   25198592u   // int idx [32768] = 131,072 B
#define WS_NEED   25329664u

// ---- top-2 (max sigma) with smaller-index tie-break ----
struct Top2 { float s1; int i1; float s2; int i2; };

__device__ __forceinline__ bool better(float sa, int ia, float sb, int ib) {
    return (sa > sb) || (sa == sb && ia < ib);
}
__device__ __forceinline__ Top2 merge2(const Top2& a, const Top2& b) {
    Top2 r;
    if (better(b.s1, b.i1, a.s1, a.i1)) {
        r.s1 = b.s1; r.i1 = b.i1;
        if (better(a.s1, a.i1, b.s2, b.i2)) { r.s2 = a.s1; r.i2 = a.i1; }
        else                                { r.s2 = b.s2; r.i2 = b.i2; }
    } else {
        r.s1 = a.s1; r.i1 = a.i1;
        if (better(b.s1, b.i1, a.s2, a.i2)) { r.s2 = b.s1; r.i2 = b.i1; }
        else                                { r.s2 = a.s2; r.i2 = a.i2; }
    }
    return r;
}

// ---- 1. z = concat(real,imag) as f16 [32768][256] ----
__global__ __launch_bounds__(256) void prep_z(const float* __restrict__ gr,
                                              const float* __restrict__ gi,
                                              _Float16* __restrict__ A) {
    int t = blockIdx.x * 256 + threadIdx.x;     // 4 elements/thread
    int base = t * 4;
    int m = base >> 8;
    int k = base & 255;
    float4 v;
    if (k < 128) v = *(const float4*)(gr + (size_t)m * 128 + k);
    else         v = *(const float4*)(gi + (size_t)m * 128 + (k - 128));
    half4v h;
    h[0] = (_Float16)v.x; h[1] = (_Float16)v.y;
    h[2] = (_Float16)v.z; h[3] = (_Float16)v.w;
    *(half4v*)(A + base) = h;
}

// ---- 2. codebook f16 [8192][256] + 0.5*||c||^2 fp32 ----
__global__ __launch_bounds__(64) void prep_c(const float* __restrict__ cb,
                                             _Float16* __restrict__ B,
                                             float* __restrict__ cnorm) {
    int v = blockIdx.x;
    int lane = threadIdx.x;                    // 0..63, 4 floats each
    float4 c = ((const float4*)(cb + (size_t)v * 256))[lane];
    half4v h;
    h[0] = (_Float16)c.x; h[1] = (_Float16)c.y;
    h[2] = (_Float16)c.z; h[3] = (_Float16)c.w;
    ((half4v*)(B + (size_t)v * 256))[lane] = h;
    float s = c.x * c.x + c.y * c.y + c.z * c.z + c.w * c.w;
    #pragma unroll
    for (int m = 32; m; m >>= 1) s += __shfl_xor(s, m);
    if (lane == 0) cnorm[v] = 0.5f * s;
}

// ---- 3. f16 GEMM + per-row top-2 argmax(sigma), NO-LDS B path ----
// R14 post-mortem: 754 us with MfmaUtil 7.5% / 70% idle -- 256 barrier-pairs
// per block each exposing load->vmcnt(0)->ds_write->barrier->ds_read. B is
// L2-resident (FETCH 26-29 MB since R10), and an MFMA B-fragment is 8
// k-consecutive f16 = one 16-B global load. So: read A and B fragments
// DIRECTLY from global (L2) into registers -- zero LDS staging, ZERO barriers
// in the main loop. One-stage software pipeline; buffer parity = s&1 is
// compile-time (g*4 even). LDS = topbuf only (2 KB); barriers only at the
// 8 per-row flushes. Datapath/flush/part layout identical to R14-proven.
__global__ __launch_bounds__(256) void gemm_argmin(const _Float16* __restrict__ A,
                                                   const _Float16* __restrict__ B,
                                                   const float* __restrict__ cnorm,
                                                   float4* __restrict__ part) {
    __shared__ __align__(16) float4 topbuf[128];       // [64 rows][2 col-halves]

    const int tid = threadIdx.x;
    const int m0 = blockIdx.x * 64;
    const int wave = tid >> 6, lane = tid & 63;
    const int wr = wave >> 1, wc = wave & 1;           // 2x2: 32 rows x 64 cols
    const int lane16 = lane & 15, quad = lane >> 4;

    // A-fragments direct from global (once): row m0+wr*32+i*16+lane16,
    // k = s*64 + ks*32 + quad*8 (8 consecutive f16 = 16 B)
    half8 af[2][4][2];   // [i][s][ks]
    #pragma unroll
    for (int i = 0; i < 2; ++i) {
        const _Float16* ar = A + (size_t)(m0 + wr * 32 + i * 16 + lane16) * 256
                               + quad * 8;
        #pragma unroll
        for (int s = 0; s < 4; ++s)
            #pragma unroll
            for (int ks = 0; ks < 2; ++ks)
                af[i][s][ks] = *(const half8*)(ar + s * 64 + ks * 32);
    }

    // B row base pointers for this lane's 4 column groups (n-tile 0)
    const _Float16* brow[4];
    #pragma unroll
    for (int j = 0; j < 4; ++j)
        brow[j] = B + (size_t)(wc * 64 + j * 16 + lane16) * 256 + quad * 8;

    // software pipeline: stage t = g*4+s; parity s&1 picks buffer
    half8 bufA[4][2], bufB[4][2];   // [j][ks]
    #pragma unroll
    for (int j = 0; j < 4; ++j)
        #pragma unroll
        for (int ks = 0; ks < 2; ++ks)
            bufA[j][ks] = *(const half8*)(brow[j] + ks * 32);   // g=0, s=0

    Top2 t2[2][4];
    #pragma unroll
    for (int i = 0; i < 2; ++i)
        #pragma unroll
        for (int r = 0; r < 4; ++r)
            t2[i][r] = Top2{-3.4e38f, 0x7fffffff, -3.4e38f, 0x7fffffff};

    for (int g = 0; g < 64; ++g) {
        const int n0 = g * 128;

        float hc[4];
        #pragma unroll
        for (int j = 0; j < 4; ++j)
            hc[j] = cnorm[n0 + wc * 64 + j * 16 + lane16];

        floatx4 acc[2][4];
        #pragma unroll
        for (int i = 0; i < 2; ++i)
            #pragma unroll
            for (int j = 0; j < 4; ++j)
                acc[i][j] = (floatx4){0.f, 0.f, 0.f, 0.f};

        #pragma unroll
        for (int s = 0; s < 4; ++s) {
            // prefetch stage t+1 into the other buffer (in flight over MFMAs)
            const int t = g * 4 + s;
            if (t < 255) {
                const int gn = (t + 1) >> 2, sn = (t + 1) & 3;
                const size_t goff = (size_t)gn * 128 * 256 + sn * 64;
                if ((s & 1) == 0) {
                    #pragma unroll
                    for (int j = 0; j < 4; ++j)
                        #pragma unroll
                        for (int ks = 0; ks < 2; ++ks)
                            bufB[j][ks] = *(const half8*)(brow[j] + goff + ks * 32);
                } else {
                    #pragma unroll
                    for (int j = 0; j < 4; ++j)
                        #pragma unroll
                        for (int ks = 0; ks < 2; ++ks)
                            bufA[j][ks] = *(const half8*)(brow[j] + goff + ks * 32);
                }
            }
            // MFMA from current buffer (parity s&1, compile-time in unroll)
            #pragma unroll
            for (int ks = 0; ks < 2; ++ks)
                #pragma unroll
                for (int i = 0; i < 2; ++i)
                    #pragma unroll
                    for (int j = 0; j < 4; ++j)
                        acc[i][j] = __builtin_amdgcn_mfma_f32_16x16x32_f16(
                            af[i][s][ks],
                            ((s & 1) == 0) ? bufA[j][ks] : bufB[j][ks],
                            acc[i][j], 0, 0, 0);
        }

        // per-g top-2 update (registers; C/D: col=lane&15, row=quad*4+reg)
        #pragma unroll
        for (int i = 0; i < 2; ++i)
            #pragma unroll
            for (int r = 0; r < 4; ++r) {
                #pragma unroll
                for (int j = 0; j < 4; ++j) {
                    float sv = acc[i][j][r] - hc[j];
                    int col = n0 + wc * 64 + j * 16 + lane16;
                    Top2& t = t2[i][r];
                    if (better(sv, col, t.s1, t.i1)) {
                        t.s2 = t.s1; t.i2 = t.i1; t.s1 = sv; t.i1 = col;
                    } else if (better(sv, col, t.s2, t.i2)) {
                        t.s2 = sv; t.i2 = col;
                    }
                }
            }

        // flush every 8 g: butterfly + cross-wave merge + part write (R14)
        if ((g & 7) == 7) {
            const int slot = g >> 3;
            #pragma unroll
            for (int i = 0; i < 2; ++i)
                #pragma unroll
                for (int r = 0; r < 4; ++r) {
                    Top2 t = t2[i][r];
                    #pragma unroll
                    for (int m = 1; m < 16; m <<= 1) {
                        Top2 o;
                        o.s1 = __shfl_xor(t.s1, m); o.i1 = __shfl_xor(t.i1, m);
                        o.s2 = __shfl_xor(t.s2, m); o.i2 = __shfl_xor(t.i2, m);
                        t = merge2(t, o);
                    }
                    if (lane16 == 0) {
                        int rl = wr * 32 + i * 16 + quad * 4 + r;   // 0..63
                        topbuf[rl * 2 + wc] =
                            make_float4(t.s1, __int_as_float(t.i1),
                                        t.s2, __int_as_float(t.i2));
                    }
                    t2[i][r] = Top2{-3.4e38f, 0x7fffffff, -3.4e38f, 0x7fffffff};
                }
            __syncthreads();
            if (tid < 64) {
                float4 e0 = topbuf[tid * 2 + 0], e1 = topbuf[tid * 2 + 1];
                Top2 a{e0.x, __float_as_int(e0.y), e0.z, __float_as_int(e0.w)};
                Top2 b{e1.x, __float_as_int(e1.y), e1.z, __float_as_int(e1.w)};
                Top2 t = merge2(a, b);
                part[(size_t)(m0 + tid) * 8 + slot] =
                    make_float4(t.s1, __int_as_float(t.i1),
                                t.s2, __int_as_float(t.i2));
            }
            __syncthreads();   // topbuf reusable next flush
        }
    }
}

// ---- 4. resolve: merge 8 partials/row, fp64-refine near-ties (R4-proven) ----
__global__ __launch_bounds__(256) void resolve(const float4* __restrict__ part,
                                               const float* __restrict__ gr,
                                               const float* __restrict__ gi,
                                               const float* __restrict__ cb,
                                               int* __restrict__ idx) {
    const int row = blockIdx.x * 256 + threadIdx.x;   // grid 128
    float4 e[8];
    #pragma unroll
    for (int j = 0; j < 8; ++j) e[j] = part[(size_t)row * 8 + j];
    Top2 t{-3.4e38f, 0x7fffffff, -3.4e38f, 0x7fffffff};
    #pragma unroll
    for (int j = 0; j < 8; ++j) {
        Top2 o{e[j].x, __float_as_int(e[j].y), e[j].z, __float_as_int(e[j].w)};
        t = merge2(t, o);
    }
    int best = t.i1;
    const float MARGIN = 0.12f;   // ~7.7 sigma of f16-screen score-diff noise
    if (t.s1 - t.s2 < MARGIN) {
        double bd = 1e300; int bi = 0x7fffffff;
        float cut = t.s1 - MARGIN;
        const float* zr = gr + (size_t)row * 128;
        const float* zi = gi + (size_t)row * 128;
        #pragma unroll
        for (int j = 0; j < 8; ++j) {
            #pragma unroll
            for (int c = 0; c < 2; ++c) {
                float sv = c ? e[j].z : e[j].x;
                int   ci = __float_as_int(c ? e[j].w : e[j].y);
                if (sv >= cut && (unsigned)ci < 8192u) {   // clamp: no wild reads
                    const float* crow = cb + (size_t)ci * 256;
                    double d = 0.0;
                    for (int k = 0; k < 128; ++k) {
                        double a = (double)zr[k] - (double)crow[k];
                        double b = (double)zi[k] - (double)crow[128 + k];
                        d += a * a + b * b;
                    }
                    if (d < bd || (d == bd && ci < bi)) { bd = d; bi = ci; }
                }
            }
        }
        if ((unsigned)bi < 8192u) best = bi;
    }
    idx[row] = ((unsigned)best < 8192u) ? best : 0;
}

// ---- 5a. zero the vq accumulator ----
__global__ void zero_vq(float* __restrict__ out, size_t vq_off) {
    out[vq_off] = 0.f;
}

// ---- 5b. gather + proposal(REAL part only) + salience + vq (one wave/row) ----
__global__ __launch_bounds__(256) void gather_epi(const int* __restrict__ idx,
                                                  const float* __restrict__ gr,
                                                  const float* __restrict__ gi,
                                                  const float* __restrict__ cb,
                                                  const float* __restrict__ salw,
                                                  const float* __restrict__ salb,
                                                  float* __restrict__ out,
                                                  size_t sal_off, size_t vq_off) {
    const int wave = threadIdx.x >> 6, lane = threadIdx.x & 63;
    const int row = blockIdx.x * 4 + wave;
    int id = idx[row];
    if ((unsigned)id >= 8192u) id = 0;   // clamp: no wild reads

    float4 c4 = ((const float4*)(cb + (size_t)id * 256))[lane];
    float4 z4 = (lane < 32) ? ((const float4*)(gr + (size_t)row * 128))[lane]
                            : ((const float4*)(gi + (size_t)row * 128))[lane - 32];

    float dx = c4.x - z4.x, dy = c4.y - z4.y, dz = c4.z - z4.z, dw = c4.w - z4.w;
    float vq = dx * dx + dy * dy + dz * dz + dw * dw;
    float4 w4 = ((const float4*)salw)[lane];
    float sal = c4.x * w4.x + c4.y * w4.y + c4.z * w4.z + c4.w * w4.w;
    #pragma unroll
    for (int m = 1; m < 64; m <<= 1) {
        vq  += __shfl_xor(vq, m);
        sal += __shfl_xor(sal, m);
    }

    // proposal: real part only — lanes 0..31 hold c[0..128) as float4s
    if (lane < 32 && (size_t)(row + 1) * 128 <= sal_off) {
        float4* op = (float4*)(out + (size_t)row * 128);
        op[lane] = c4;
    }
    if (lane == 0 && sal_off + row < vq_off)
        out[sal_off + row] = sal + salb[0];

    __shared__ float vqs[4];
    if (lane == 0) vqs[wave] = vq;
    __syncthreads();
    if (threadIdx.x == 0) {
        float p = (vqs[0] + vqs[1] + vqs[2] + vqs[3]) * (1.25f / 8388608.f);
        atomicAdd(out + vq_off, p);
    }
}

extern "C" void kernel_launch(void* const* d_in, const int* in_sizes, int n_in,
                              void* d_out, int out_size, void* d_ws, size_t ws_size,
                              hipStream_t stream) {
    const float* gr = (const float*)d_in[0];   // gw_real  [8,4096,128]
    const float* gi = (const float*)d_in[1];   // gw_imag  [8,4096,128]
    const float* cb = (const float*)d_in[2];   // codebook [8192,256]
    const float* sw = (const float*)d_in[3];   // sal_w    [1,256]
    const float* sb = (const float*)d_in[4];   // sal_b    [1]
    float* out = (float*)d_out;

    // Output offsets (out_size = 4,227,073 floats:
    // proposal-real 4,194,304 | salience 32,768 | vq_loss 1).
    size_t vq_off  = (size_t)out_size - 1;
    size_t sal_off = (size_t)out_size - 1 - 32768;

    char* base = (char*)d_ws;
    int*  idxb = (int*)(base + IDX_OFF);
    _Float16* A    = (_Float16*)(base + A_OFF);
    _Float16* Bq   = (_Float16*)(base + B_OFF);
    float*    cn   = (float*)   (base + CN_OFF);
    float4*   part = (float4*)  (base + PART_OFF);

    prep_z<<<8192, 256, 0, stream>>>(gr, gi, A);
    prep_c<<<8192, 64, 0, stream>>>(cb, Bq, cn);
    gemm_argmin<<<512, 256, 0, stream>>>(A, Bq, cn, part);
    resolve<<<128, 256, 0, stream>>>(part, gr, gi, cb, idxb);
    zero_vq<<<1, 1, 0, stream>>>(out, vq_off);
    gather_epi<<<8192, 256, 0, stream>>>(idxb, gr, gi, cb, sw, sb, out,
                                         sal_off, vq_off);
}